// Round 1
// baseline (48.644 us; speedup 1.0000x reference)
//
#include <hip/hip_runtime.h>

#define TT 65536          // total tokens = 8 * 8192
#define HDIM 512
#define NE 4
#define SEQL 8192
#define NBATCH 8
#define TPB 64            // tokens per block
#define NBLK (TT / TPB)   // 1024 blocks
#define BPB (SEQL / TPB)  // 128 blocks per batch
#define TPW 16            // tokens per wave (4 waves/block)

// One wave handles one token per iteration: 64 lanes x (2 x float4) = 512 floats.
// Logits accumulated in fp64 so top-k ordering matches a float64 numpy reference
// (near-tie argmax flips under fp32 would fail the exact-index check).
__global__ __launch_bounds__(256) void moe_gate_main(
    const float* __restrict__ x, const float* __restrict__ w,
    float* __restrict__ out, float* __restrict__ ws)
{
  const int lane = threadIdx.x & 63;
  const int wave = threadIdx.x >> 6;

  // Per-lane weight fragments: w[e][4*lane..4*lane+3] and w[e][256+4*lane..]
  float4 wA[NE], wB[NE];
#pragma unroll
  for (int e = 0; e < NE; ++e) {
    wA[e] = *(const float4*)(w + e * HDIM + 4 * lane);
    wB[e] = *(const float4*)(w + e * HDIM + 256 + 4 * lane);
  }

  float ssum[NE] = {0.f, 0.f, 0.f, 0.f};  // sum of softmax scores (this wave's tokens)
  float cnt[NE]  = {0.f, 0.f, 0.f, 0.f};  // top-2 selection counts

  const int t0 = blockIdx.x * TPB + wave * TPW;  // all TPW tokens in same batch
  const float4* xp = (const float4*)x;
  const size_t base = (size_t)t0 * (HDIM / 4);

  float4 xA = xp[base + lane];
  float4 xB = xp[base + 64 + lane];

  for (int i = 0; i < TPW; ++i) {
    // prefetch next token's row before consuming current
    float4 nA, nB;
    if (i + 1 < TPW) {
      size_t nb = base + (size_t)(i + 1) * (HDIM / 4);
      nA = xp[nb + lane];
      nB = xp[nb + 64 + lane];
    }

    double acc[NE];
#pragma unroll
    for (int e = 0; e < NE; ++e) {
      double a = (double)xA.x * (double)wA[e].x;
      a += (double)xA.y * (double)wA[e].y;
      a += (double)xA.z * (double)wA[e].z;
      a += (double)xA.w * (double)wA[e].w;
      a += (double)xB.x * (double)wB[e].x;
      a += (double)xB.y * (double)wB[e].y;
      a += (double)xB.z * (double)wB[e].z;
      a += (double)xB.w * (double)wB[e].w;
      acc[e] = a;
    }
    // butterfly reduce across 64 lanes; afterwards all lanes hold full logits
#pragma unroll
    for (int m = 1; m < 64; m <<= 1) {
#pragma unroll
      for (int e = 0; e < NE; ++e) acc[e] += __shfl_xor(acc[e], m, 64);
    }

    // top-1 / top-2 on fp64 logits; strict '>' ascending scan = lowest-index tie-break
    int i0 = 0; double v0 = acc[0];
#pragma unroll
    for (int e = 1; e < NE; ++e) { if (acc[e] > v0) { v0 = acc[e]; i0 = e; } }
    int i1 = -1; double v1 = -1.0e300;
#pragma unroll
    for (int e = 0; e < NE; ++e) { if (e != i0 && acc[e] > v1) { v1 = acc[e]; i1 = e; } }

    // softmax (fp32 is plenty for the 6e-2 weight threshold)
    float u[NE]; float psum = 0.f;
#pragma unroll
    for (int e = 0; e < NE; ++e) { u[e] = __expf((float)(acc[e] - v0)); psum += u[e]; }
    const float inv = 1.0f / psum;
#pragma unroll
    for (int e = 0; e < NE; ++e) ssum[e] += u[e] * inv;
#pragma unroll
    for (int e = 0; e < NE; ++e)
      cnt[e] += ((e == i0) ? 1.f : 0.f) + ((e == i1) ? 1.f : 0.f);

    const float p0 = inv;  // exp(0) * inv
    const float u1 = (i1 == 0) ? u[0] : (i1 == 1) ? u[1] : (i1 == 2) ? u[2] : u[3];
    const float p1 = u1 * inv;
    const float denom = p0 + p1 + 1e-20f;
    const float w0 = p0 / denom, w1 = p1 / denom;

    if (lane == 0) {
      const int t = t0 + i;
      out[2 * t]     = (float)i0;          // topk_idx as float
      out[2 * t + 1] = (float)i1;
      out[2 * TT + 2 * t]     = w0;        // topk_weight
      out[2 * TT + 2 * t + 1] = w1;
    }
    xA = nA; xB = nB;
  }

  // deterministic block-level combine of aux partials (no atomics)
  __shared__ float part[4][8];
  if (lane == 0) {
#pragma unroll
    for (int e = 0; e < NE; ++e) { part[wave][e] = ssum[e]; part[wave][4 + e] = cnt[e]; }
  }
  __syncthreads();
  if (threadIdx.x < 8) {
    float s = 0.f;
#pragma unroll
    for (int w2 = 0; w2 < 4; ++w2) s += part[w2][threadIdx.x];
    ws[(size_t)blockIdx.x * 8 + threadIdx.x] = s;  // [block][0..3]=score sums, [4..7]=counts
  }
}

// Single-block reduction over 1024 block-partials (8 KB read) -> aux_loss
__global__ void moe_gate_aux(const float* __restrict__ ws, float* __restrict__ out)
{
  const int j = threadIdx.x;
  double term = 0.0;
  if (j < 32) {
    const int b = j >> 2, e = j & 3;
    float ss = 0.f, cc = 0.f;
    for (int k = 0; k < BPB; ++k) {
      const float* p = ws + (size_t)(b * BPB + k) * 8;
      ss += p[e];
      cc += p[4 + e];
    }
    // ce = cc / (seq*K/E) = cc/4096 ; mean score = ss/8192
    term = ((double)cc / 4096.0) * ((double)ss / 8192.0);
  }
  for (int m = 1; m < 64; m <<= 1) term += __shfl_xor(term, m, 64);
  if (j == 0) out[4 * TT] = (float)(0.1 * term / 8.0);  // mean over 8 batches * ALPHA
}

extern "C" void kernel_launch(void* const* d_in, const int* in_sizes, int n_in,
                              void* d_out, int out_size, void* d_ws, size_t ws_size,
                              hipStream_t stream) {
  const float* x = (const float*)d_in[0];   // [8,8192,512] fp32
  const float* w = (const float*)d_in[1];   // [4,512] fp32
  float* out = (float*)d_out;               // idx[131072] | weight[131072] | aux[1]
  float* ws  = (float*)d_ws;                // 1024 * 8 floats = 32 KB

  moe_gate_main<<<NBLK, 256, 0, stream>>>(x, w, out, ws);
  moe_gate_aux<<<1, 64, 0, stream>>>(ws, out);
}

// Round 2
// 36.562 us; speedup vs baseline: 1.3304x; 1.3304x over previous
//
#include <hip/hip_runtime.h>

#define TT 65536          // total tokens = 8 * 8192
#define HDIM 512
#define NE 4
#define SEQL 8192
#define TPB 64            // tokens per block
#define NBLK (TT / TPB)   // 1024 blocks
#define BPB (SEQL / TPB)  // 128 blocks per batch
#define TPW 16            // tokens per wave (4 waves/block)

// One wave per token-iteration: 64 lanes x (2 x float4) = the 512-float row.
// fp64 logits (exact-index safety vs np reference). Reduction restructured:
//   reduce-scatter (masks 1,2) -> single fp64/lane -> tree (4,8,16,32)
//   -> LDS allgather of the 4 logits. ~17 DS ops/token vs 48 before.
__global__ __launch_bounds__(256, 4) void moe_gate_main(
    const float* __restrict__ x, const float* __restrict__ w,
    float* __restrict__ out, float* __restrict__ ws)
{
  const int lane = threadIdx.x & 63;
  const int wave = threadIdx.x >> 6;
  const int b0 = lane & 1;
  const int b1 = (lane >> 1) & 1;

  __shared__ double lg[4][4];   // per-wave logit allgather slot (128 B)
  __shared__ float part[4][8];  // per-wave aux partials

  // fp64 weight fragments: w[e][4*lane..+3] and w[e][256+4*lane..+3]
  double wd[NE][8];
#pragma unroll
  for (int e = 0; e < NE; ++e) {
    float4 a = *(const float4*)(w + e * HDIM + 4 * lane);
    float4 b = *(const float4*)(w + e * HDIM + 256 + 4 * lane);
    wd[e][0] = a.x; wd[e][1] = a.y; wd[e][2] = a.z; wd[e][3] = a.w;
    wd[e][4] = b.x; wd[e][5] = b.y; wd[e][6] = b.z; wd[e][7] = b.w;
  }

  float ssum[NE] = {0.f, 0.f, 0.f, 0.f};
  float cnt[NE]  = {0.f, 0.f, 0.f, 0.f};

  const int t0 = blockIdx.x * TPB + wave * TPW;
  const float4* xp = (const float4*)x;
  const size_t base = (size_t)t0 * (HDIM / 4);

  float4 xA = xp[base + lane];
  float4 xB = xp[base + 64 + lane];

  for (int i = 0; i < TPW; ++i) {
    float4 nA, nB;
    if (i + 1 < TPW) {
      size_t nb = base + (size_t)(i + 1) * (HDIM / 4);
      nA = xp[nb + lane];
      nB = xp[nb + 64 + lane];
    }

    // per-lane fp64 partials (convert x at use; no fp64 x array)
    double p0 = 0.0, p1 = 0.0, p2 = 0.0, p3 = 0.0;
    {
      const float xe[8] = {xA.x, xA.y, xA.z, xA.w, xB.x, xB.y, xB.z, xB.w};
#pragma unroll
      for (int j = 0; j < 8; ++j) {
        const double td = (double)xe[j];
        p0 += td * wd[0][j];
        p1 += td * wd[1][j];
        p2 += td * wd[2][j];
        p3 += td * wd[3][j];
      }
    }

    // reduce-scatter stage 1 (mask 1): lane(b0) keeps experts {2b0, 2b0+1}
    const double r0 = __shfl_xor(b0 ? p0 : p2, 1);
    const double r1 = __shfl_xor(b0 ? p1 : p3, 1);
    const double s0 = (b0 ? p2 : p0) + r0;   // expert 2*b0
    const double s1 = (b0 ? p3 : p1) + r1;   // expert 2*b0+1
    // stage 2 (mask 2): keep expert em = 2*b0 + b1
    const double r2 = __shfl_xor(b1 ? s0 : s1, 2);
    double v = (b1 ? s1 : s0) + r2;
    // tree across the 16 groups
    v += __shfl_xor(v, 4);
    v += __shfl_xor(v, 8);
    v += __shfl_xor(v, 16);
    v += __shfl_xor(v, 32);

    // allgather the 4 logits via per-wave LDS (wave-synchronous, in-order DS)
    if (lane < 4) lg[wave][2 * (lane & 1) + ((lane >> 1) & 1)] = v;
    const double L0 = lg[wave][0];
    const double L1 = lg[wave][1];
    const double L2 = lg[wave][2];
    const double L3 = lg[wave][3];

    // top-1 / top-2 on fp64 logits; strict '>' ascending scan = lowest-index tie-break
    const double acc[NE] = {L0, L1, L2, L3};
    int i0 = 0; double v0 = acc[0];
#pragma unroll
    for (int e = 1; e < NE; ++e) { if (acc[e] > v0) { v0 = acc[e]; i0 = e; } }
    int i1 = -1; double v1 = -1.0e300;
#pragma unroll
    for (int e = 0; e < NE; ++e) { if (e != i0 && acc[e] > v1) { v1 = acc[e]; i1 = e; } }

    // softmax in fp32
    float u[NE]; float psum = 0.f;
#pragma unroll
    for (int e = 0; e < NE; ++e) { u[e] = __expf((float)(acc[e] - v0)); psum += u[e]; }
    const float inv = 1.0f / psum;
#pragma unroll
    for (int e = 0; e < NE; ++e) ssum[e] += u[e] * inv;
#pragma unroll
    for (int e = 0; e < NE; ++e)
      cnt[e] += ((e == i0) ? 1.f : 0.f) + ((e == i1) ? 1.f : 0.f);

    const float pp0 = inv;  // exp(0) * inv
    const float u1 = (i1 == 0) ? u[0] : (i1 == 1) ? u[1] : (i1 == 2) ? u[2] : u[3];
    const float pp1 = u1 * inv;
    const float denom = pp0 + pp1 + 1e-20f;
    const float w0 = pp0 / denom, w1 = pp1 / denom;

    if (lane == 0) {
      const int t = t0 + i;
      out[2 * t]     = (float)i0;
      out[2 * t + 1] = (float)i1;
      out[2 * TT + 2 * t]     = w0;
      out[2 * TT + 2 * t + 1] = w1;
    }
    xA = nA; xB = nB;
  }

  // deterministic block-level combine of aux partials (no atomics)
  if (lane == 0) {
#pragma unroll
    for (int e = 0; e < NE; ++e) { part[wave][e] = ssum[e]; part[wave][4 + e] = cnt[e]; }
  }
  __syncthreads();
  if (threadIdx.x < 8) {
    float s = 0.f;
#pragma unroll
    for (int w2 = 0; w2 < 4; ++w2) s += part[w2][threadIdx.x];
    ws[(size_t)blockIdx.x * 8 + threadIdx.x] = s;  // [0..3]=score sums, [4..7]=counts
  }
}

// Single-block reduction over 1024 block-partials (8 KB) -> aux_loss
__global__ void moe_gate_aux(const float* __restrict__ ws, float* __restrict__ out)
{
  const int j = threadIdx.x;
  double term = 0.0;
  if (j < 32) {
    const int b = j >> 2, e = j & 3;
    float ss = 0.f, cc = 0.f;
    for (int k = 0; k < BPB; ++k) {
      const float* p = ws + (size_t)(b * BPB + k) * 8;
      ss += p[e];
      cc += p[4 + e];
    }
    term = ((double)cc / 4096.0) * ((double)ss / 8192.0);
  }
  for (int m = 1; m < 64; m <<= 1) term += __shfl_xor(term, m, 64);
  if (j == 0) out[4 * TT] = (float)(0.1 * term / 8.0);
}

extern "C" void kernel_launch(void* const* d_in, const int* in_sizes, int n_in,
                              void* d_out, int out_size, void* d_ws, size_t ws_size,
                              hipStream_t stream) {
  const float* x = (const float*)d_in[0];   // [8,8192,512] fp32
  const float* w = (const float*)d_in[1];   // [4,512] fp32
  float* out = (float*)d_out;               // idx[131072] | weight[131072] | aux[1]
  float* ws  = (float*)d_ws;                // 1024 * 8 floats = 32 KB

  moe_gate_main<<<NBLK, 256, 0, stream>>>(x, w, out, ws);
  moe_gate_aux<<<1, 64, 0, stream>>>(ws, out);
}